// Round 10
// baseline (238.866 us; speedup 1.0000x reference)
//
#include <hip/hip_runtime.h>

// LIF neuron forward: T=8 timesteps, x shape [T*B, C, H, W] = [256,128,32,32] f32.
// Recurrence per spatial element:
//   mem = beta*mem + (1-beta)*x_t ; spike = (mem >= 0.3*Vth)*Vth ;
//   mem -= spike ; out_t = spike/0.05
//
// History:
//  R1: 1 float4/thread: 87 us, ~3.3 TB/s CU-side (vs 6.29 copy / 6.65 fill
//      measured in-process). Pipes idle.
//  R3: nt stores: 100 us (reverted). R4/R5: sched_barrier / memory clobber /
//      dataflow-pin all failed to raise in-flight loads (VGPR stuck ~24).
//  R6: grid-stride, occupancy 62->31%: ~neutral. R7: burst x2: 82 us (-6%).
//      R8: burst x4: 82 us (saturated).
//  R8 audit: VGPR 20..36 across all rounds proves the compiler NEVER kept
//      more than ~2 loads in flight/wave -- every MLP experiment was silently
//      rewritten. Little's law: 2 x 2 KB x ~20 waves/CU / ~1.3 us loaded
//      latency = ~3.2 TB/s = the plateau. Latency-bound at MLP=2 is the one
//      theory never actually tested.
//  R9: indivisible asm block (8x global_load_dwordx4 + vmcnt(0)): CRASHED --
//      outputs lacked early-clobber, so an output tuple aliased a later
//      load's address VGPR; async writeback corrupted the address -> fault.
//  R10: same block with "=&v" early-clobber outputs. Tell: VGPR >= 48.
//
// Bit-exactness notes (decisions flip 0<->20, zero flips allowed):
//  - beta = f32(exp(f32(-0.05))) = 0x1.E7078Cp-1 (verified absmax 0.0 in
//    R1/R3..R8).
//  - mem update uses __fmul_rn/__fadd_rn (no FMA contraction; matches numpy).
//  - (1.0f - beta) exact; Vth clamp round-trips to 1.0f; vth/0.05f == 20.0f.

#define T_STEPS 8
#define S_ELEMS (32 * 128 * 32 * 32)     // per-timestep elements = 4,194,304
#define S4 (S_ELEMS / 4)                 // float4 per timestep = 1,048,576
#define PLANE_BYTES (S_ELEMS * 4u)       // 16 MiB
#define BLOCK 256

typedef float f32x4 __attribute__((ext_vector_type(4)));

__global__ __launch_bounds__(BLOCK) void lif_fwd_kernel(
    const f32x4* __restrict__ x, const float* __restrict__ vth_ptr,
    f32x4* __restrict__ out) {
  const unsigned i = blockIdx.x * BLOCK + threadIdx.x;  // float4 column index

  // Vth clamp (no-grad): relu(Vth - 5e-4) + 5e-4, all f32 rn. (scalar path)
  const float vth_raw = vth_ptr[0];
  const float vth = __fadd_rn(fmaxf(__fsub_rn(vth_raw, 0.0005f), 0.0f), 0.0005f);
  const float thr = __fmul_rn(0.3f, vth);      // ALPHA * Vth
  const float outval = __fdiv_rn(vth, 0.05f);  // Vth / DELTA_T (== 20.0f)

  const float beta = 0x1.E7078Cp-1f;        // f32(exp(f32(-0.05)))
  const float omb = __fsub_rn(1.0f, beta);  // exact

  // Byte offsets of this column in each of the 8 t-planes (fit in u32: <134M).
  const unsigned b0 = i * 16u;
  const unsigned o0 = b0 + 0u * PLANE_BYTES, o1 = b0 + 1u * PLANE_BYTES,
                 o2 = b0 + 2u * PLANE_BYTES, o3 = b0 + 3u * PLANE_BYTES,
                 o4 = b0 + 4u * PLANE_BYTES, o5 = b0 + 5u * PLANE_BYTES,
                 o6 = b0 + 6u * PLANE_BYTES, o7 = b0 + 7u * PLANE_BYTES;

  // Indivisible load block: 8 dwordx4 loads back-to-back (8 KB/wave in
  // flight), one vmcnt(0). "=&v" (early-clobber) guarantees no output tuple
  // aliases any input address VGPR or the saddr pair -- loads write back
  // asynchronously, so outputs are live from the FIRST instruction on.
  f32x4 x0, x1, x2, x3, x4, x5, x6, x7;
  asm volatile(
      "global_load_dwordx4 %0, %8, %16\n\t"
      "global_load_dwordx4 %1, %9, %16\n\t"
      "global_load_dwordx4 %2, %10, %16\n\t"
      "global_load_dwordx4 %3, %11, %16\n\t"
      "global_load_dwordx4 %4, %12, %16\n\t"
      "global_load_dwordx4 %5, %13, %16\n\t"
      "global_load_dwordx4 %6, %14, %16\n\t"
      "global_load_dwordx4 %7, %15, %16\n\t"
      "s_waitcnt vmcnt(0)"
      : "=&v"(x0), "=&v"(x1), "=&v"(x2), "=&v"(x3), "=&v"(x4), "=&v"(x5),
        "=&v"(x6), "=&v"(x7)
      : "v"(o0), "v"(o1), "v"(o2), "v"(o3), "v"(o4), "v"(o5), "v"(o6), "v"(o7),
        "s"(x)
      : "memory");

  // Recurrence + stores (stores pipeline freely; no loads remain).
  float m0 = 0.f, m1 = 0.f, m2 = 0.f, m3 = 0.f;
  const f32x4 xv[T_STEPS] = {x0, x1, x2, x3, x4, x5, x6, x7};
#pragma unroll
  for (int t = 0; t < T_STEPS; ++t) {
    m0 = __fadd_rn(__fmul_rn(beta, m0), __fmul_rn(omb, xv[t].x));
    m1 = __fadd_rn(__fmul_rn(beta, m1), __fmul_rn(omb, xv[t].y));
    m2 = __fadd_rn(__fmul_rn(beta, m2), __fmul_rn(omb, xv[t].z));
    m3 = __fadd_rn(__fmul_rn(beta, m3), __fmul_rn(omb, xv[t].w));
    const bool s0 = (m0 >= thr), s1 = (m1 >= thr), s2 = (m2 >= thr),
               s3 = (m3 >= thr);
    f32x4 o;
    o.x = s0 ? outval : 0.0f;
    o.y = s1 ? outval : 0.0f;
    o.z = s2 ? outval : 0.0f;
    o.w = s3 ? outval : 0.0f;
    if (s0) m0 = __fsub_rn(m0, vth);
    if (s1) m1 = __fsub_rn(m1, vth);
    if (s2) m2 = __fsub_rn(m2, vth);
    if (s3) m3 = __fsub_rn(m3, vth);
    out[i + (size_t)t * S4] = o;
  }
}

extern "C" void kernel_launch(void* const* d_in, const int* in_sizes, int n_in,
                              void* d_out, int out_size, void* d_ws,
                              size_t ws_size, hipStream_t stream) {
  const f32x4* x = (const f32x4*)d_in[0];
  const float* vth = (const float*)d_in[1];
  f32x4* out = (f32x4*)d_out;
  lif_fwd_kernel<<<S4 / BLOCK, BLOCK, 0, stream>>>(x, vth, out);
}